// Round 11
// baseline (1155.592 us; speedup 1.0000x reference)
//
#include <hip/hip_runtime.h>
#include <hip/hip_fp16.h>
#include <math.h>
#include <float.h>

// ---------------------------------------------------------------------------
// GCN on MI355X. N=50000, E=1.6M, widths 128 -> 64 (x8) -> 4.
// CSR (dst-sorted, src only) built per call, XCD-partitioned count/fill.
// hs (GEMM output, gather source) stored PLANAR: two [n][32] fp16 planes
// (3.2MB each). Aggregation runs as TWO passes per layer, one per plane, so
// each pass's random-gather working set fits the 4MiB per-XCD L2 (vs 6.4MB
// single-pass -> ~40% L3 misses at ~1.5TB/s random = the old bottleneck).
// Per pass: wave per node, two half-wave groups each gather 32 features of
// alternating edges (1x64B line per edge), cross-group shfl reduce at end.
// Activations fp16 (fp32 accumulate). dinv folded into epilogues.
// Final layer: GEMM to 4 then 4-wide agg. Softmax over node axis.
// ---------------------------------------------------------------------------

#define NPART 8
#define BPP   104   // blocks per partition for count/fill

typedef float f4 __attribute__((ext_vector_type(4)));

// ---------------- degree / CSR build (XCD-partitioned) ----------------

__global__ __launch_bounds__(256) void k_count(const int* __restrict__ dst,
                                               unsigned* __restrict__ deg,
                                               int E, int chunk) {
    int part = blockIdx.x & (NPART - 1);
    int q = blockIdx.x >> 3;
    int lo = part * chunk, hi = lo + chunk;
    for (int e = q * 256 + threadIdx.x; e < E; e += 256 * BPP) {
        int d = dst[e];
        if (d >= lo && d < hi) atomicAdd(&deg[d], 1u);
    }
}

__global__ __launch_bounds__(256) void k_dinv(const unsigned* __restrict__ deg,
                                              float* __restrict__ dinv, int n) {
    int i = blockIdx.x * 256 + threadIdx.x;
    if (i < n) dinv[i] = rsqrtf(1.0f + (float)deg[i]);
}

__global__ __launch_bounds__(256) void k_scan1(const unsigned* __restrict__ deg,
                                               int* __restrict__ row_start,
                                               unsigned* __restrict__ bsum, int n) {
    __shared__ unsigned t[256];
    int i = blockIdx.x * 256 + threadIdx.x;
    unsigned v = (i < n) ? deg[i] : 0u;
    t[threadIdx.x] = v;
    __syncthreads();
    #pragma unroll
    for (int off = 1; off < 256; off <<= 1) {
        unsigned u = (threadIdx.x >= (unsigned)off) ? t[threadIdx.x - off] : 0u;
        __syncthreads();
        t[threadIdx.x] += u;
        __syncthreads();
    }
    if (i < n) row_start[i] = (int)(t[threadIdx.x] - v);
    if (threadIdx.x == 255) bsum[blockIdx.x] = t[255];
}

__global__ __launch_bounds__(256) void k_scan2(unsigned* __restrict__ bsum,
                                               int* __restrict__ row_start,
                                               int nb, int n) {
    __shared__ unsigned t[256];
    unsigned v = (threadIdx.x < (unsigned)nb) ? bsum[threadIdx.x] : 0u;
    t[threadIdx.x] = v;
    __syncthreads();
    #pragma unroll
    for (int off = 1; off < 256; off <<= 1) {
        unsigned u = (threadIdx.x >= (unsigned)off) ? t[threadIdx.x - off] : 0u;
        __syncthreads();
        t[threadIdx.x] += u;
        __syncthreads();
    }
    if (threadIdx.x < (unsigned)nb) bsum[threadIdx.x] = t[threadIdx.x] - v;
    if (threadIdx.x == 255) row_start[n] = (int)t[255];
}

__global__ __launch_bounds__(256) void k_scan3(int* __restrict__ row_start,
                                               const unsigned* __restrict__ bsum, int n) {
    int i = blockIdx.x * 256 + threadIdx.x;
    if (i < n) row_start[i] += (int)bsum[blockIdx.x];
}

__global__ __launch_bounds__(256) void k_fill(const int* __restrict__ src,
                                              const int* __restrict__ dst,
                                              const int* __restrict__ row_start,
                                              unsigned* __restrict__ cursor,
                                              int* __restrict__ csr_src,
                                              int E, int chunk) {
    int part = blockIdx.x & (NPART - 1);
    int q = blockIdx.x >> 3;
    int lo = part * chunk, hi = lo + chunk;
    for (int e = q * 256 + threadIdx.x; e < E; e += 256 * BPP) {
        int d = dst[e];
        if (d >= lo && d < hi) {
            int s = src[e];
            unsigned pos = atomicAdd(&cursor[d], 1u);
            csr_src[row_start[d] + (int)pos] = s;
        }
    }
}

// ---- GEMM layer1 (128->64): 16 rows/block, 4 rows/wave, ILP-4.
//      Output written PLANAR: plane (lane>=32), feature lane&31. ----

__global__ __launch_bounds__(256) void k_gemm64_f32(const float* __restrict__ x,
                                                    const float* __restrict__ W,
                                                    const float* __restrict__ dinv,
                                                    __half* __restrict__ hs, int n) {
    __shared__ float Wl[128 * 64];
    {
        const f4* Wv = (const f4*)W;
        f4* Wlv = (f4*)Wl;
        for (int idx = threadIdx.x; idx < 128 * 16; idx += 256) Wlv[idx] = Wv[idx];
    }
    __syncthreads();
    int wave = threadIdx.x >> 6, lane = threadIdx.x & 63;
    size_t po = (lane >= 32) ? (size_t)n * 32 : 0;  // plane offset
    int fl = lane & 31;
    int i0 = blockIdx.x * 16 + wave * 4;
    if (i0 >= n) return;
    if (i0 + 3 < n) {
        const f4* r0 = (const f4*)(x + (size_t)(i0 + 0) * 128);
        const f4* r1 = (const f4*)(x + (size_t)(i0 + 1) * 128);
        const f4* r2 = (const f4*)(x + (size_t)(i0 + 2) * 128);
        const f4* r3 = (const f4*)(x + (size_t)(i0 + 3) * 128);
        float a0 = 0.f, a1 = 0.f, a2 = 0.f, a3 = 0.f;
        #pragma unroll
        for (int k4 = 0; k4 < 32; ++k4) {
            f4 v0 = __builtin_nontemporal_load(&r0[k4]);
            f4 v1 = __builtin_nontemporal_load(&r1[k4]);
            f4 v2 = __builtin_nontemporal_load(&r2[k4]);
            f4 v3 = __builtin_nontemporal_load(&r3[k4]);
            float w0 = Wl[(k4 * 4 + 0) * 64 + lane];
            float w1 = Wl[(k4 * 4 + 1) * 64 + lane];
            float w2 = Wl[(k4 * 4 + 2) * 64 + lane];
            float w3 = Wl[(k4 * 4 + 3) * 64 + lane];
            a0 += v0.x * w0 + v0.y * w1 + v0.z * w2 + v0.w * w3;
            a1 += v1.x * w0 + v1.y * w1 + v1.z * w2 + v1.w * w3;
            a2 += v2.x * w0 + v2.y * w1 + v2.z * w2 + v2.w * w3;
            a3 += v3.x * w0 + v3.y * w1 + v3.z * w2 + v3.w * w3;
        }
        hs[po + (size_t)(i0 + 0) * 32 + fl] = __float2half(a0 * dinv[i0 + 0]);
        hs[po + (size_t)(i0 + 1) * 32 + fl] = __float2half(a1 * dinv[i0 + 1]);
        hs[po + (size_t)(i0 + 2) * 32 + fl] = __float2half(a2 * dinv[i0 + 2]);
        hs[po + (size_t)(i0 + 3) * 32 + fl] = __float2half(a3 * dinv[i0 + 3]);
    } else {
        for (int i = i0; i < n && i < i0 + 4; ++i) {
            const f4* r = (const f4*)(x + (size_t)i * 128);
            float acc = 0.f;
            #pragma unroll
            for (int k4 = 0; k4 < 32; ++k4) {
                f4 v = r[k4];
                acc += v.x * Wl[(k4 * 4 + 0) * 64 + lane];
                acc += v.y * Wl[(k4 * 4 + 1) * 64 + lane];
                acc += v.z * Wl[(k4 * 4 + 2) * 64 + lane];
                acc += v.w * Wl[(k4 * 4 + 3) * 64 + lane];
            }
            hs[po + (size_t)i * 32 + fl] = __float2half(acc * dinv[i]);
        }
    }
}

// ---- GEMM layers 2..8 (64->64 fp16 in): planar output, same structure ----

__global__ __launch_bounds__(256) void k_gemm64_f16(const __half* __restrict__ xh,
                                                    const float* __restrict__ W,
                                                    const float* __restrict__ dinv,
                                                    __half* __restrict__ hs, int n) {
    __shared__ float Wl[64 * 64];
    {
        const f4* Wv = (const f4*)W;
        f4* Wlv = (f4*)Wl;
        for (int idx = threadIdx.x; idx < 64 * 16; idx += 256) Wlv[idx] = Wv[idx];
    }
    __syncthreads();
    int wave = threadIdx.x >> 6, lane = threadIdx.x & 63;
    size_t po = (lane >= 32) ? (size_t)n * 32 : 0;
    int fl = lane & 31;
    int i0 = blockIdx.x * 16 + wave * 4;
    if (i0 >= n) return;
    if (i0 + 3 < n) {
        const unsigned* r0 = (const unsigned*)(xh + (size_t)(i0 + 0) * 64);
        const unsigned* r1 = (const unsigned*)(xh + (size_t)(i0 + 1) * 64);
        const unsigned* r2 = (const unsigned*)(xh + (size_t)(i0 + 2) * 64);
        const unsigned* r3 = (const unsigned*)(xh + (size_t)(i0 + 3) * 64);
        float a0 = 0.f, a1 = 0.f, a2 = 0.f, a3 = 0.f;
        #pragma unroll
        for (int k2 = 0; k2 < 32; ++k2) {
            unsigned u0 = __builtin_nontemporal_load(&r0[k2]);
            unsigned u1 = __builtin_nontemporal_load(&r1[k2]);
            unsigned u2 = __builtin_nontemporal_load(&r2[k2]);
            unsigned u3 = __builtin_nontemporal_load(&r3[k2]);
            float w0 = Wl[(k2 * 2 + 0) * 64 + lane];
            float w1 = Wl[(k2 * 2 + 1) * 64 + lane];
            float2 v0 = __half22float2(*(__half2*)&u0);
            float2 v1 = __half22float2(*(__half2*)&u1);
            float2 v2 = __half22float2(*(__half2*)&u2);
            float2 v3 = __half22float2(*(__half2*)&u3);
            a0 += v0.x * w0 + v0.y * w1;
            a1 += v1.x * w0 + v1.y * w1;
            a2 += v2.x * w0 + v2.y * w1;
            a3 += v3.x * w0 + v3.y * w1;
        }
        hs[po + (size_t)(i0 + 0) * 32 + fl] = __float2half(a0 * dinv[i0 + 0]);
        hs[po + (size_t)(i0 + 1) * 32 + fl] = __float2half(a1 * dinv[i0 + 1]);
        hs[po + (size_t)(i0 + 2) * 32 + fl] = __float2half(a2 * dinv[i0 + 2]);
        hs[po + (size_t)(i0 + 3) * 32 + fl] = __float2half(a3 * dinv[i0 + 3]);
    } else {
        for (int i = i0; i < n && i < i0 + 4; ++i) {
            const __half2* r = (const __half2*)(xh + (size_t)i * 64);
            float acc = 0.f;
            #pragma unroll
            for (int k2 = 0; k2 < 32; ++k2) {
                float2 v = __half22float2(r[k2]);
                acc += v.x * Wl[(k2 * 2 + 0) * 64 + lane];
                acc += v.y * Wl[(k2 * 2 + 1) * 64 + lane];
            }
            hs[po + (size_t)i * 32 + fl] = __float2half(acc * dinv[i]);
        }
    }
}

// ---- small GEMM: h4[i] = (xh[i,:64] @ W[64,4]) * dinv[i] ----
__global__ __launch_bounds__(256) void k_gemm4(const __half* __restrict__ xh,
                                               const float* __restrict__ W,
                                               const float* __restrict__ dinv,
                                               float4* __restrict__ h4, int n) {
    __shared__ float Wl[256];
    for (int idx = threadIdx.x; idx < 256; idx += 256) Wl[idx] = W[idx];
    __syncthreads();
    int i = blockIdx.x * 256 + threadIdx.x;
    if (i >= n) return;
    const __half2* ar = (const __half2*)(xh + (size_t)i * 64);
    float a0 = 0.f, a1 = 0.f, a2 = 0.f, a3 = 0.f;
    #pragma unroll
    for (int k2 = 0; k2 < 32; ++k2) {
        float2 v = __half22float2(ar[k2]);
        int k = k2 * 2;
        a0 += v.x * Wl[k * 4 + 0] + v.y * Wl[(k + 1) * 4 + 0];
        a1 += v.x * Wl[k * 4 + 1] + v.y * Wl[(k + 1) * 4 + 1];
        a2 += v.x * Wl[k * 4 + 2] + v.y * Wl[(k + 1) * 4 + 2];
        a3 += v.x * Wl[k * 4 + 3] + v.y * Wl[(k + 1) * 4 + 3];
    }
    float di = dinv[i];
    h4[i] = make_float4(a0 * di, a1 * di, a2 * di, a3 * di);
}

// ------- agg pass over ONE 32-feature plane (3.2MB gather working set) -------
// wave per node; half-wave group sub (0/1) gathers alternating edges' rows;
// cross-group shfl_xor(32) combines. outP = out + P*32, biasP = bias + P*32.

__global__ __launch_bounds__(256) void k_agg32(const __half* __restrict__ plane,
                                               const float* __restrict__ dinv,
                                               const int* __restrict__ row_start,
                                               const int* __restrict__ csr_src,
                                               const float* __restrict__ biasP,
                                               __half* __restrict__ outP, int n) {
    int wid = threadIdx.x >> 6;
    int lane = threadIdx.x & 63;
    int sub = lane >> 5;        // half-wave group
    int fl = lane & 31;         // feature within plane
    int gw = blockIdx.x * 4 + wid;
    if (gw >= n) return;
    float acc = (sub == 0) ? __half2float(plane[(size_t)gw * 32 + fl]) : 0.f;  // self
    int s = row_start[gw], e = row_start[gw + 1];
    int sb = s;
    for (; sb + 16 <= e; sb += 16) {   // 16 edges per iter (8 per group)
        float v[8];
        #pragma unroll
        for (int k = 0; k < 8; ++k) {
            int idx = csr_src[sb + 2 * k + sub];
            v[k] = __half2float(plane[(size_t)idx * 32 + fl]);
        }
        acc += ((v[0] + v[1]) + (v[2] + v[3])) + ((v[4] + v[5]) + (v[6] + v[7]));
    }
    for (int t = sb + sub; t < e; t += 2)
        acc += __half2float(plane[(size_t)csr_src[t] * 32 + fl]);
    acc += __shfl_xor(acc, 32);        // combine the two groups
    if (sub == 0) {
        acc = acc * dinv[gw] + biasP[fl];
        outP[(size_t)gw * 64 + fl] = __float2half(fmaxf(acc, 0.f));
    }
}

// ------- agg 4-wide (final): z[d] = (Σ h4[s] + h4[d])*dinv[d] + b3 -------

__global__ __launch_bounds__(256) void k_agg4(const float4* __restrict__ h4,
                                              const float* __restrict__ dinv,
                                              const int* __restrict__ row_start,
                                              const int* __restrict__ csr_src,
                                              const float* __restrict__ b3,
                                              float4* __restrict__ z, int n) {
    int i = blockIdx.x * 256 + threadIdx.x;
    if (i >= n) return;
    float4 self = h4[i];
    float a0 = self.x, a1 = self.y, a2 = self.z, a3 = self.w;
    int s = row_start[i], e = row_start[i + 1];
    int slot = s;
    for (; slot + 4 <= e; slot += 4) {
        int s0 = csr_src[slot + 0];
        int s1 = csr_src[slot + 1];
        int s2 = csr_src[slot + 2];
        int s3 = csr_src[slot + 3];
        float4 v0 = h4[s0], v1 = h4[s1], v2 = h4[s2], v3 = h4[s3];
        a0 += v0.x + v1.x + v2.x + v3.x;
        a1 += v0.y + v1.y + v2.y + v3.y;
        a2 += v0.z + v1.z + v2.z + v3.z;
        a3 += v0.w + v1.w + v2.w + v3.w;
    }
    for (; slot < e; ++slot) {
        float4 v = h4[csr_src[slot]];
        a0 += v.x; a1 += v.y; a2 += v.z; a3 += v.w;
    }
    float di = dinv[i];
    z[i] = make_float4(a0 * di + b3[0], a1 * di + b3[1],
                       a2 * di + b3[2], a3 * di + b3[3]);
}

// ---------------- softmax over node axis (per column, C=4) ----------------

__device__ inline unsigned encf(float f) {
    unsigned u = __float_as_uint(f);
    return (u & 0x80000000u) ? ~u : (u | 0x80000000u);
}
__device__ inline float decf(unsigned e) {
    return (e & 0x80000000u) ? __uint_as_float(e & 0x7FFFFFFFu) : __uint_as_float(~e);
}

__global__ __launch_bounds__(256) void k_max(const float4* __restrict__ z,
                                             unsigned* __restrict__ gmax, int n) {
    float m0 = -FLT_MAX, m1 = -FLT_MAX, m2 = -FLT_MAX, m3 = -FLT_MAX;
    for (int i = blockIdx.x * 256 + threadIdx.x; i < n; i += gridDim.x * 256) {
        float4 v = z[i];
        m0 = fmaxf(m0, v.x); m1 = fmaxf(m1, v.y);
        m2 = fmaxf(m2, v.z); m3 = fmaxf(m3, v.w);
    }
    #pragma unroll
    for (int off = 32; off; off >>= 1) {
        m0 = fmaxf(m0, __shfl_xor(m0, off));
        m1 = fmaxf(m1, __shfl_xor(m1, off));
        m2 = fmaxf(m2, __shfl_xor(m2, off));
        m3 = fmaxf(m3, __shfl_xor(m3, off));
    }
    if ((threadIdx.x & 63) == 0) {
        atomicMax(&gmax[0], encf(m0));
        atomicMax(&gmax[1], encf(m1));
        atomicMax(&gmax[2], encf(m2));
        atomicMax(&gmax[3], encf(m3));
    }
}

__global__ __launch_bounds__(256) void k_exp(const float4* __restrict__ z,
                                             float4* __restrict__ out,
                                             const unsigned* __restrict__ gmax,
                                             float* __restrict__ gsum, int n) {
    float M0 = decf(gmax[0]), M1 = decf(gmax[1]), M2 = decf(gmax[2]), M3 = decf(gmax[3]);
    float s0 = 0.f, s1 = 0.f, s2 = 0.f, s3 = 0.f;
    for (int i = blockIdx.x * 256 + threadIdx.x; i < n; i += gridDim.x * 256) {
        float4 v = z[i];
        float4 e;
        e.x = expf(v.x - M0); e.y = expf(v.y - M1);
        e.z = expf(v.z - M2); e.w = expf(v.w - M3);
        out[i] = e;
        s0 += e.x; s1 += e.y; s2 += e.z; s3 += e.w;
    }
    #pragma unroll
    for (int off = 32; off; off >>= 1) {
        s0 += __shfl_xor(s0, off);
        s1 += __shfl_xor(s1, off);
        s2 += __shfl_xor(s2, off);
        s3 += __shfl_xor(s3, off);
    }
    if ((threadIdx.x & 63) == 0) {
        atomicAdd(&gsum[0], s0);
        atomicAdd(&gsum[1], s1);
        atomicAdd(&gsum[2], s2);
        atomicAdd(&gsum[3], s3);
    }
}

__global__ __launch_bounds__(256) void k_norm(float4* __restrict__ out,
                                              const float* __restrict__ gsum, int n) {
    float r0 = 1.f / gsum[0], r1 = 1.f / gsum[1], r2 = 1.f / gsum[2], r3 = 1.f / gsum[3];
    for (int i = blockIdx.x * 256 + threadIdx.x; i < n; i += gridDim.x * 256) {
        float4 v = out[i];
        v.x *= r0; v.y *= r1; v.z *= r2; v.w *= r3;
        out[i] = v;
    }
}

// ---------------------------------------------------------------------------

extern "C" void kernel_launch(void* const* d_in, const int* in_sizes, int n_in,
                              void* d_out, int out_size, void* d_ws, size_t ws_size,
                              hipStream_t stream) {
    const float* x0 = (const float*)d_in[0];
    const int* ei = (const int*)d_in[1];
    const float* W1 = (const float*)d_in[2];
    const float* b1 = (const float*)d_in[3];
    const float* W2 = (const float*)d_in[4];
    const float* b2 = (const float*)d_in[5];
    const float* W3 = (const float*)d_in[6];
    const float* b3 = (const float*)d_in[7];

    const int n = in_sizes[0] / 128;   // 50000
    const int E = in_sizes[1] / 2;     // 1600000
    const int* src = ei;
    const int* dst = ei + E;
    const int chunk = (n + NPART - 1) / NPART;

    char* ws = (char*)d_ws;
    size_t off = 0;
    auto alloc = [&](size_t bytes) -> void* {
        void* p = (void*)(ws + off);
        off = (off + bytes + 255) & ~(size_t)255;
        return p;
    };

    // zeroed region first (deg, cursor, gmax, gsum)
    unsigned* deg    = (unsigned*)alloc((size_t)n * 4);
    unsigned* cursor = (unsigned*)alloc((size_t)n * 4);
    unsigned* gmax   = (unsigned*)alloc(16);
    float*    gsum   = (float*)alloc(16);
    size_t zero_bytes = off;

    float* dinv      = (float*)alloc((size_t)n * 4);
    int*   row_start = (int*)alloc((size_t)(n + 1) * 4);
    unsigned* bsum   = (unsigned*)alloc(1024 * 4);
    int*   csr_src   = (int*)alloc((size_t)E * 4);
    __half* hbuf     = (__half*)alloc((size_t)n * 64 * 2);  // 2 planes of [n][32]
    __half* xbuf     = (__half*)alloc((size_t)n * 64 * 2);  // normal [n][64]
    float4* h4buf    = (float4*)alloc((size_t)n * 16);
    float4* zbuf     = (float4*)alloc((size_t)n * 16);

    hipMemsetAsync(deg, 0, zero_bytes, stream);

    const int nbN = (n + 255) / 256;

    // CSR build (count/fill XCD-partitioned by dst range)
    k_count<<<NPART * BPP, 256, 0, stream>>>(dst, deg, E, chunk);
    k_dinv<<<nbN, 256, 0, stream>>>(deg, dinv, n);
    k_scan1<<<nbN, 256, 0, stream>>>(deg, row_start, bsum, n);
    k_scan2<<<1, 256, 0, stream>>>(bsum, row_start, nbN, n);
    k_scan3<<<nbN, 256, 0, stream>>>(row_start, bsum, n);
    k_fill<<<NPART * BPP, 256, 0, stream>>>(src, dst, row_start, cursor, csr_src, E, chunk);

    const int nbG = (n + 15) / 16;        // gemm blocks (16 rows/block)
    const int nbA = (n + 3) / 4;          // agg blocks (4 waves/block)

    __half* plane0 = hbuf;
    __half* plane1 = hbuf + (size_t)n * 32;

    // layer 1: 128 -> 64 (fp32 input)
    k_gemm64_f32<<<nbG, 256, 0, stream>>>(x0, W1, dinv, hbuf, n);
    k_agg32<<<nbA, 256, 0, stream>>>(plane0, dinv, row_start, csr_src, b1,      xbuf,      n);
    k_agg32<<<nbA, 256, 0, stream>>>(plane1, dinv, row_start, csr_src, b1 + 32, xbuf + 32, n);

    // layers 2..8: 64 -> 64, shared W2 (fp16 activations)
    for (int l = 0; l < 7; ++l) {
        k_gemm64_f16<<<nbG, 256, 0, stream>>>(xbuf, W2, dinv, hbuf, n);
        k_agg32<<<nbA, 256, 0, stream>>>(plane0, dinv, row_start, csr_src, b2,      xbuf,      n);
        k_agg32<<<nbA, 256, 0, stream>>>(plane1, dinv, row_start, csr_src, b2 + 32, xbuf + 32, n);
    }

    // layer 9: gemm to 4 features first, then 4-wide agg (fp32)
    k_gemm4<<<nbN, 256, 0, stream>>>(xbuf, W3, dinv, h4buf, n);
    k_agg4<<<nbN, 256, 0, stream>>>(h4buf, dinv, row_start, csr_src, b3, zbuf, n);

    // softmax over node axis
    k_max<<<256, 256, 0, stream>>>(zbuf, gmax, n);
    k_exp<<<256, 256, 0, stream>>>(zbuf, (float4*)d_out, gmax, gsum, n);
    k_norm<<<256, 256, 0, stream>>>((float4*)d_out, gsum, n);
}

// Round 12
// 1008.691 us; speedup vs baseline: 1.1456x; 1.1456x over previous
//
#include <hip/hip_runtime.h>
#include <hip/hip_fp16.h>
#include <math.h>
#include <float.h>

// ---------------------------------------------------------------------------
// GCN on MI355X. N=50000, E=1.6M, widths 128 -> 64 (x8) -> 4.
// R9 structure (best known: 857us) + half2 agg gathers (2 edges per wave-wide
// load instruction: lanes 0-31 = even edge, 32-63 = odd edge, each lane holds
// feature pair 2*fl,2*fl+1; shfl_xor(32) combine). Index loads wave-uniform
// (scalar pipe, readfirstlane wid). CSR built per call (XCD-partitioned
// count/fill). Activations fp16, fp32 accumulate, dinv folded into epilogues.
// Final layer: GEMM to 4 then 4-wide agg. Softmax over node axis.
// ---------------------------------------------------------------------------

#define NPART 8
#define BPP   104   // blocks per partition for count/fill

typedef float f4 __attribute__((ext_vector_type(4)));

// ---------------- degree / CSR build (XCD-partitioned) ----------------

__global__ __launch_bounds__(256) void k_count(const int* __restrict__ dst,
                                               unsigned* __restrict__ deg,
                                               int E, int chunk) {
    int part = blockIdx.x & (NPART - 1);
    int q = blockIdx.x >> 3;
    int lo = part * chunk, hi = lo + chunk;
    for (int e = q * 256 + threadIdx.x; e < E; e += 256 * BPP) {
        int d = dst[e];
        if (d >= lo && d < hi) atomicAdd(&deg[d], 1u);
    }
}

__global__ __launch_bounds__(256) void k_dinv(const unsigned* __restrict__ deg,
                                              float* __restrict__ dinv, int n) {
    int i = blockIdx.x * 256 + threadIdx.x;
    if (i < n) dinv[i] = rsqrtf(1.0f + (float)deg[i]);
}

__global__ __launch_bounds__(256) void k_scan1(const unsigned* __restrict__ deg,
                                               int* __restrict__ row_start,
                                               unsigned* __restrict__ bsum, int n) {
    __shared__ unsigned t[256];
    int i = blockIdx.x * 256 + threadIdx.x;
    unsigned v = (i < n) ? deg[i] : 0u;
    t[threadIdx.x] = v;
    __syncthreads();
    #pragma unroll
    for (int off = 1; off < 256; off <<= 1) {
        unsigned u = (threadIdx.x >= (unsigned)off) ? t[threadIdx.x - off] : 0u;
        __syncthreads();
        t[threadIdx.x] += u;
        __syncthreads();
    }
    if (i < n) row_start[i] = (int)(t[threadIdx.x] - v);
    if (threadIdx.x == 255) bsum[blockIdx.x] = t[255];
}

__global__ __launch_bounds__(256) void k_scan2(unsigned* __restrict__ bsum,
                                               int* __restrict__ row_start,
                                               int nb, int n) {
    __shared__ unsigned t[256];
    unsigned v = (threadIdx.x < (unsigned)nb) ? bsum[threadIdx.x] : 0u;
    t[threadIdx.x] = v;
    __syncthreads();
    #pragma unroll
    for (int off = 1; off < 256; off <<= 1) {
        unsigned u = (threadIdx.x >= (unsigned)off) ? t[threadIdx.x - off] : 0u;
        __syncthreads();
        t[threadIdx.x] += u;
        __syncthreads();
    }
    if (threadIdx.x < (unsigned)nb) bsum[threadIdx.x] = t[threadIdx.x] - v;
    if (threadIdx.x == 255) row_start[n] = (int)t[255];
}

__global__ __launch_bounds__(256) void k_scan3(int* __restrict__ row_start,
                                               const unsigned* __restrict__ bsum, int n) {
    int i = blockIdx.x * 256 + threadIdx.x;
    if (i < n) row_start[i] += (int)bsum[blockIdx.x];
}

__global__ __launch_bounds__(256) void k_fill(const int* __restrict__ src,
                                              const int* __restrict__ dst,
                                              const int* __restrict__ row_start,
                                              unsigned* __restrict__ cursor,
                                              int* __restrict__ csr_src,
                                              int E, int chunk) {
    int part = blockIdx.x & (NPART - 1);
    int q = blockIdx.x >> 3;
    int lo = part * chunk, hi = lo + chunk;
    for (int e = q * 256 + threadIdx.x; e < E; e += 256 * BPP) {
        int d = dst[e];
        if (d >= lo && d < hi) {
            int s = src[e];
            unsigned pos = atomicAdd(&cursor[d], 1u);
            csr_src[row_start[d] + (int)pos] = s;
        }
    }
}

// ---- GEMM layer1 (128->64): 16 rows/block, 4 rows/wave, ILP-4 ----

__global__ __launch_bounds__(256) void k_gemm64_f32(const float* __restrict__ x,
                                                    const float* __restrict__ W,
                                                    const float* __restrict__ dinv,
                                                    __half* __restrict__ hs, int n) {
    __shared__ float Wl[128 * 64];
    {
        const f4* Wv = (const f4*)W;
        f4* Wlv = (f4*)Wl;
        for (int idx = threadIdx.x; idx < 128 * 16; idx += 256) Wlv[idx] = Wv[idx];
    }
    __syncthreads();
    int wave = threadIdx.x >> 6, lane = threadIdx.x & 63;
    int i0 = blockIdx.x * 16 + wave * 4;
    if (i0 >= n) return;
    if (i0 + 3 < n) {
        const f4* r0 = (const f4*)(x + (size_t)(i0 + 0) * 128);
        const f4* r1 = (const f4*)(x + (size_t)(i0 + 1) * 128);
        const f4* r2 = (const f4*)(x + (size_t)(i0 + 2) * 128);
        const f4* r3 = (const f4*)(x + (size_t)(i0 + 3) * 128);
        float a0 = 0.f, a1 = 0.f, a2 = 0.f, a3 = 0.f;
        #pragma unroll
        for (int k4 = 0; k4 < 32; ++k4) {
            f4 v0 = __builtin_nontemporal_load(&r0[k4]);
            f4 v1 = __builtin_nontemporal_load(&r1[k4]);
            f4 v2 = __builtin_nontemporal_load(&r2[k4]);
            f4 v3 = __builtin_nontemporal_load(&r3[k4]);
            float w0 = Wl[(k4 * 4 + 0) * 64 + lane];
            float w1 = Wl[(k4 * 4 + 1) * 64 + lane];
            float w2 = Wl[(k4 * 4 + 2) * 64 + lane];
            float w3 = Wl[(k4 * 4 + 3) * 64 + lane];
            a0 += v0.x * w0 + v0.y * w1 + v0.z * w2 + v0.w * w3;
            a1 += v1.x * w0 + v1.y * w1 + v1.z * w2 + v1.w * w3;
            a2 += v2.x * w0 + v2.y * w1 + v2.z * w2 + v2.w * w3;
            a3 += v3.x * w0 + v3.y * w1 + v3.z * w2 + v3.w * w3;
        }
        hs[(size_t)(i0 + 0) * 64 + lane] = __float2half(a0 * dinv[i0 + 0]);
        hs[(size_t)(i0 + 1) * 64 + lane] = __float2half(a1 * dinv[i0 + 1]);
        hs[(size_t)(i0 + 2) * 64 + lane] = __float2half(a2 * dinv[i0 + 2]);
        hs[(size_t)(i0 + 3) * 64 + lane] = __float2half(a3 * dinv[i0 + 3]);
    } else {
        for (int i = i0; i < n && i < i0 + 4; ++i) {
            const f4* r = (const f4*)(x + (size_t)i * 128);
            float acc = 0.f;
            #pragma unroll
            for (int k4 = 0; k4 < 32; ++k4) {
                f4 v = r[k4];
                acc += v.x * Wl[(k4 * 4 + 0) * 64 + lane];
                acc += v.y * Wl[(k4 * 4 + 1) * 64 + lane];
                acc += v.z * Wl[(k4 * 4 + 2) * 64 + lane];
                acc += v.w * Wl[(k4 * 4 + 3) * 64 + lane];
            }
            hs[(size_t)i * 64 + lane] = __float2half(acc * dinv[i]);
        }
    }
}

// ---- GEMM layers 2..8 (64->64 fp16 in): same structure ----

__global__ __launch_bounds__(256) void k_gemm64_f16(const __half* __restrict__ xh,
                                                    const float* __restrict__ W,
                                                    const float* __restrict__ dinv,
                                                    __half* __restrict__ hs, int n) {
    __shared__ float Wl[64 * 64];
    {
        const f4* Wv = (const f4*)W;
        f4* Wlv = (f4*)Wl;
        for (int idx = threadIdx.x; idx < 64 * 16; idx += 256) Wlv[idx] = Wv[idx];
    }
    __syncthreads();
    int wave = threadIdx.x >> 6, lane = threadIdx.x & 63;
    int i0 = blockIdx.x * 16 + wave * 4;
    if (i0 >= n) return;
    if (i0 + 3 < n) {
        const unsigned* r0 = (const unsigned*)(xh + (size_t)(i0 + 0) * 64);
        const unsigned* r1 = (const unsigned*)(xh + (size_t)(i0 + 1) * 64);
        const unsigned* r2 = (const unsigned*)(xh + (size_t)(i0 + 2) * 64);
        const unsigned* r3 = (const unsigned*)(xh + (size_t)(i0 + 3) * 64);
        float a0 = 0.f, a1 = 0.f, a2 = 0.f, a3 = 0.f;
        #pragma unroll
        for (int k2 = 0; k2 < 32; ++k2) {
            unsigned u0 = __builtin_nontemporal_load(&r0[k2]);
            unsigned u1 = __builtin_nontemporal_load(&r1[k2]);
            unsigned u2 = __builtin_nontemporal_load(&r2[k2]);
            unsigned u3 = __builtin_nontemporal_load(&r3[k2]);
            float w0 = Wl[(k2 * 2 + 0) * 64 + lane];
            float w1 = Wl[(k2 * 2 + 1) * 64 + lane];
            float2 v0 = __half22float2(*(__half2*)&u0);
            float2 v1 = __half22float2(*(__half2*)&u1);
            float2 v2 = __half22float2(*(__half2*)&u2);
            float2 v3 = __half22float2(*(__half2*)&u3);
            a0 += v0.x * w0 + v0.y * w1;
            a1 += v1.x * w0 + v1.y * w1;
            a2 += v2.x * w0 + v2.y * w1;
            a3 += v3.x * w0 + v3.y * w1;
        }
        hs[(size_t)(i0 + 0) * 64 + lane] = __float2half(a0 * dinv[i0 + 0]);
        hs[(size_t)(i0 + 1) * 64 + lane] = __float2half(a1 * dinv[i0 + 1]);
        hs[(size_t)(i0 + 2) * 64 + lane] = __float2half(a2 * dinv[i0 + 2]);
        hs[(size_t)(i0 + 3) * 64 + lane] = __float2half(a3 * dinv[i0 + 3]);
    } else {
        for (int i = i0; i < n && i < i0 + 4; ++i) {
            const __half2* r = (const __half2*)(xh + (size_t)i * 64);
            float acc = 0.f;
            #pragma unroll
            for (int k2 = 0; k2 < 32; ++k2) {
                float2 v = __half22float2(r[k2]);
                acc += v.x * Wl[(k2 * 2 + 0) * 64 + lane];
                acc += v.y * Wl[(k2 * 2 + 1) * 64 + lane];
            }
            hs[(size_t)i * 64 + lane] = __float2half(acc * dinv[i]);
        }
    }
}

// ---- small GEMM: h4[i] = (xh[i,:64] @ W[64,4]) * dinv[i] ----
__global__ __launch_bounds__(256) void k_gemm4(const __half* __restrict__ xh,
                                               const float* __restrict__ W,
                                               const float* __restrict__ dinv,
                                               float4* __restrict__ h4, int n) {
    __shared__ float Wl[256];
    for (int idx = threadIdx.x; idx < 256; idx += 256) Wl[idx] = W[idx];
    __syncthreads();
    int i = blockIdx.x * 256 + threadIdx.x;
    if (i >= n) return;
    const __half2* ar = (const __half2*)(xh + (size_t)i * 64);
    float a0 = 0.f, a1 = 0.f, a2 = 0.f, a3 = 0.f;
    #pragma unroll
    for (int k2 = 0; k2 < 32; ++k2) {
        float2 v = __half22float2(ar[k2]);
        int k = k2 * 2;
        a0 += v.x * Wl[k * 4 + 0] + v.y * Wl[(k + 1) * 4 + 0];
        a1 += v.x * Wl[k * 4 + 1] + v.y * Wl[(k + 1) * 4 + 1];
        a2 += v.x * Wl[k * 4 + 2] + v.y * Wl[(k + 1) * 4 + 2];
        a3 += v.x * Wl[k * 4 + 3] + v.y * Wl[(k + 1) * 4 + 3];
    }
    float di = dinv[i];
    h4[i] = make_float4(a0 * di, a1 * di, a2 * di, a3 * di);
}

// ------- agg 64-wide fp16, half2 gathers (2 edges per load instruction) -------
// wave per node (gw wave-uniform via readfirstlane -> scalar index loads).
// lane = 32*sub + fl: sub picks edge parity, fl picks feature pair 2fl,2fl+1.
// Per 16-edge batch: 16 scalar index loads + 8 wave-wide half2 gathers.
// Cross-group combine via shfl_xor(32); self/dinv/bias/relu in group 0.

__global__ __launch_bounds__(256) void k_agg64h(const __half* __restrict__ hs,
                                                const float* __restrict__ dinv,
                                                const int* __restrict__ row_start,
                                                const int* __restrict__ csr_src,
                                                const float* __restrict__ bias,
                                                __half* __restrict__ out, int n) {
    int wid = __builtin_amdgcn_readfirstlane((int)(threadIdx.x >> 6));
    int lane = threadIdx.x & 63;
    int sub = lane >> 5;
    int fl = lane & 31;
    int gw = blockIdx.x * 4 + wid;
    if (gw >= n) return;
    const __half2* h2 = (const __half2*)hs;   // row stride = 32 half2
    float ax = 0.f, ay = 0.f;
    int s = row_start[gw], e = row_start[gw + 1];
    int sb = s;
    for (; sb + 16 <= e; sb += 16) {
        int idx[16];
        #pragma unroll
        for (int j = 0; j < 16; ++j) idx[j] = csr_src[sb + j];
        float2 v[8];
        #pragma unroll
        for (int k = 0; k < 8; ++k)
            v[k] = __half22float2(h2[(size_t)idx[2 * k + sub] * 32 + fl]);
        ax += ((v[0].x + v[1].x) + (v[2].x + v[3].x)) +
              ((v[4].x + v[5].x) + (v[6].x + v[7].x));
        ay += ((v[0].y + v[1].y) + (v[2].y + v[3].y)) +
              ((v[4].y + v[5].y) + (v[6].y + v[7].y));
    }
    for (; sb + 2 <= e; sb += 2) {            // pairs: one edge per group
        float2 v = __half22float2(h2[(size_t)csr_src[sb + sub] * 32 + fl]);
        ax += v.x; ay += v.y;
    }
    if (sb < e && sub == 0) {                 // odd last edge: group 0 only
        float2 v = __half22float2(h2[(size_t)csr_src[sb] * 32 + fl]);
        ax += v.x; ay += v.y;
    }
    ax += __shfl_xor(ax, 32);
    ay += __shfl_xor(ay, 32);
    if (sub == 0) {
        float2 sv = __half22float2(h2[(size_t)gw * 32 + fl]);  // self (prescaled)
        float di = dinv[gw];
        float o0 = fmaxf((ax + sv.x) * di + bias[2 * fl + 0], 0.f);
        float o1 = fmaxf((ay + sv.y) * di + bias[2 * fl + 1], 0.f);
        ((__half2*)out)[(size_t)gw * 32 + fl] = __floats2half2_rn(o0, o1);
    }
}

// ------- agg 4-wide (final): z[d] = (Σ h4[s] + h4[d])*dinv[d] + b3 -------

__global__ __launch_bounds__(256) void k_agg4(const float4* __restrict__ h4,
                                              const float* __restrict__ dinv,
                                              const int* __restrict__ row_start,
                                              const int* __restrict__ csr_src,
                                              const float* __restrict__ b3,
                                              float4* __restrict__ z, int n) {
    int i = blockIdx.x * 256 + threadIdx.x;
    if (i >= n) return;
    float4 self = h4[i];
    float a0 = self.x, a1 = self.y, a2 = self.z, a3 = self.w;
    int s = row_start[i], e = row_start[i + 1];
    int slot = s;
    for (; slot + 4 <= e; slot += 4) {
        int s0 = csr_src[slot + 0];
        int s1 = csr_src[slot + 1];
        int s2 = csr_src[slot + 2];
        int s3 = csr_src[slot + 3];
        float4 v0 = h4[s0], v1 = h4[s1], v2 = h4[s2], v3 = h4[s3];
        a0 += v0.x + v1.x + v2.x + v3.x;
        a1 += v0.y + v1.y + v2.y + v3.y;
        a2 += v0.z + v1.z + v2.z + v3.z;
        a3 += v0.w + v1.w + v2.w + v3.w;
    }
    for (; slot < e; ++slot) {
        float4 v = h4[csr_src[slot]];
        a0 += v.x; a1 += v.y; a2 += v.z; a3 += v.w;
    }
    float di = dinv[i];
    z[i] = make_float4(a0 * di + b3[0], a1 * di + b3[1],
                       a2 * di + b3[2], a3 * di + b3[3]);
}

// ---------------- softmax over node axis (per column, C=4) ----------------

__device__ inline unsigned encf(float f) {
    unsigned u = __float_as_uint(f);
    return (u & 0x80000000u) ? ~u : (u | 0x80000000u);
}
__device__ inline float decf(unsigned e) {
    return (e & 0x80000000u) ? __uint_as_float(e & 0x7FFFFFFFu) : __uint_as_float(~e);
}

__global__ __launch_bounds__(256) void k_max(const float4* __restrict__ z,
                                             unsigned* __restrict__ gmax, int n) {
    float m0 = -FLT_MAX, m1 = -FLT_MAX, m2 = -FLT_MAX, m3 = -FLT_MAX;
    for (int i = blockIdx.x * 256 + threadIdx.x; i < n; i += gridDim.x * 256) {
        float4 v = z[i];
        m0 = fmaxf(m0, v.x); m1 = fmaxf(m1, v.y);
        m2 = fmaxf(m2, v.z); m3 = fmaxf(m3, v.w);
    }
    #pragma unroll
    for (int off = 32; off; off >>= 1) {
        m0 = fmaxf(m0, __shfl_xor(m0, off));
        m1 = fmaxf(m1, __shfl_xor(m1, off));
        m2 = fmaxf(m2, __shfl_xor(m2, off));
        m3 = fmaxf(m3, __shfl_xor(m3, off));
    }
    if ((threadIdx.x & 63) == 0) {
        atomicMax(&gmax[0], encf(m0));
        atomicMax(&gmax[1], encf(m1));
        atomicMax(&gmax[2], encf(m2));
        atomicMax(&gmax[3], encf(m3));
    }
}

__global__ __launch_bounds__(256) void k_exp(const float4* __restrict__ z,
                                             float4* __restrict__ out,
                                             const unsigned* __restrict__ gmax,
                                             float* __restrict__ gsum, int n) {
    float M0 = decf(gmax[0]), M1 = decf(gmax[1]), M2 = decf(gmax[2]), M3 = decf(gmax[3]);
    float s0 = 0.f, s1 = 0.f, s2 = 0.f, s3 = 0.f;
    for (int i = blockIdx.x * 256 + threadIdx.x; i < n; i += gridDim.x * 256) {
        float4 v = z[i];
        float4 e;
        e.x = expf(v.x - M0); e.y = expf(v.y - M1);
        e.z = expf(v.z - M2); e.w = expf(v.w - M3);
        out[i] = e;
        s0 += e.x; s1 += e.y; s2 += e.z; s3 += e.w;
    }
    #pragma unroll
    for (int off = 32; off; off >>= 1) {
        s0 += __shfl_xor(s0, off);
        s1 += __shfl_xor(s1, off);
        s2 += __shfl_xor(s2, off);
        s3 += __shfl_xor(s3, off);
    }
    if ((threadIdx.x & 63) == 0) {
        atomicAdd(&gsum[0], s0);
        atomicAdd(&gsum[1], s1);
        atomicAdd(&gsum[2], s2);
        atomicAdd(&gsum[3], s3);
    }
}

__global__ __launch_bounds__(256) void k_norm(float4* __restrict__ out,
                                              const float* __restrict__ gsum, int n) {
    float r0 = 1.f / gsum[0], r1 = 1.f / gsum[1], r2 = 1.f / gsum[2], r3 = 1.f / gsum[3];
    for (int i = blockIdx.x * 256 + threadIdx.x; i < n; i += gridDim.x * 256) {
        float4 v = out[i];
        v.x *= r0; v.y *= r1; v.z *= r2; v.w *= r3;
        out[i] = v;
    }
}

// ---------------------------------------------------------------------------

extern "C" void kernel_launch(void* const* d_in, const int* in_sizes, int n_in,
                              void* d_out, int out_size, void* d_ws, size_t ws_size,
                              hipStream_t stream) {
    const float* x0 = (const float*)d_in[0];
    const int* ei = (const int*)d_in[1];
    const float* W1 = (const float*)d_in[2];
    const float* b1 = (const float*)d_in[3];
    const float* W2 = (const float*)d_in[4];
    const float* b2 = (const float*)d_in[5];
    const float* W3 = (const float*)d_in[6];
    const float* b3 = (const float*)d_in[7];

    const int n = in_sizes[0] / 128;   // 50000
    const int E = in_sizes[1] / 2;     // 1600000
    const int* src = ei;
    const int* dst = ei + E;
    const int chunk = (n + NPART - 1) / NPART;

    char* ws = (char*)d_ws;
    size_t off = 0;
    auto alloc = [&](size_t bytes) -> void* {
        void* p = (void*)(ws + off);
        off = (off + bytes + 255) & ~(size_t)255;
        return p;
    };

    // zeroed region first (deg, cursor, gmax, gsum)
    unsigned* deg    = (unsigned*)alloc((size_t)n * 4);
    unsigned* cursor = (unsigned*)alloc((size_t)n * 4);
    unsigned* gmax   = (unsigned*)alloc(16);
    float*    gsum   = (float*)alloc(16);
    size_t zero_bytes = off;

    float* dinv      = (float*)alloc((size_t)n * 4);
    int*   row_start = (int*)alloc((size_t)(n + 1) * 4);
    unsigned* bsum   = (unsigned*)alloc(1024 * 4);
    int*   csr_src   = (int*)alloc((size_t)E * 4);
    __half* hbuf     = (__half*)alloc((size_t)n * 64 * 2);
    __half* xbuf     = (__half*)alloc((size_t)n * 64 * 2);
    float4* h4buf    = (float4*)alloc((size_t)n * 16);
    float4* zbuf     = (float4*)alloc((size_t)n * 16);

    hipMemsetAsync(deg, 0, zero_bytes, stream);

    const int nbN = (n + 255) / 256;

    // CSR build (count/fill XCD-partitioned by dst range)
    k_count<<<NPART * BPP, 256, 0, stream>>>(dst, deg, E, chunk);
    k_dinv<<<nbN, 256, 0, stream>>>(deg, dinv, n);
    k_scan1<<<nbN, 256, 0, stream>>>(deg, row_start, bsum, n);
    k_scan2<<<1, 256, 0, stream>>>(bsum, row_start, nbN, n);
    k_scan3<<<nbN, 256, 0, stream>>>(row_start, bsum, n);
    k_fill<<<NPART * BPP, 256, 0, stream>>>(src, dst, row_start, cursor, csr_src, E, chunk);

    const int nbG = (n + 15) / 16;        // gemm blocks (16 rows/block)
    const int nbA = (n + 3) / 4;          // agg blocks (4 waves/block)

    // layer 1: 128 -> 64 (fp32 input)
    k_gemm64_f32<<<nbG, 256, 0, stream>>>(x0, W1, dinv, hbuf, n);
    k_agg64h<<<nbA, 256, 0, stream>>>(hbuf, dinv, row_start, csr_src, b1, xbuf, n);

    // layers 2..8: 64 -> 64, shared W2 (fp16 activations)
    for (int l = 0; l < 7; ++l) {
        k_gemm64_f16<<<nbG, 256, 0, stream>>>(xbuf, W2, dinv, hbuf, n);
        k_agg64h<<<nbA, 256, 0, stream>>>(hbuf, dinv, row_start, csr_src, b2, xbuf, n);
    }

    // layer 9: gemm to 4 features first, then 4-wide agg (fp32)
    k_gemm4<<<nbN, 256, 0, stream>>>(xbuf, W3, dinv, h4buf, n);
    k_agg4<<<nbN, 256, 0, stream>>>(h4buf, dinv, row_start, csr_src, b3, zbuf, n);

    // softmax over node axis
    k_max<<<256, 256, 0, stream>>>(zbuf, gmax, n);
    k_exp<<<256, 256, 0, stream>>>(zbuf, (float4*)d_out, gmax, gsum, n);
    k_norm<<<256, 256, 0, stream>>>((float4*)d_out, gsum, n);
}

// Round 13
// 845.299 us; speedup vs baseline: 1.3671x; 1.1933x over previous
//
#include <hip/hip_runtime.h>
#include <hip/hip_fp16.h>
#include <math.h>
#include <float.h>

// ---------------------------------------------------------------------------
// GCN on MI355X. N=50000, E=1.6M, widths 128 -> 64 (x8) -> 4.
// R9 structure (best: 857us) + src-tile-grouped CSR: histogram/scan over
// (dst, src_tile) with T=4 tiles of 12500 nodes (1.6MB fp16 window each).
// Each row's adjacency comes out grouped by src tile -> the agg's random
// gathers sweep a moving ~2-tile (~3.2MB) hot window that fits per-XCD L2,
// instead of uniform-random over 6.4MB. Agg inner loop IDENTICAL to R9
// (one node/wave, scalar index loads via readfirstlane, 16-deep unroll).
// Count: single unpartitioned pass. Fill: XCD-partitioned by dst as before.
// Activations fp16 (fp32 accum), dinv folded into epilogues. Final layer:
// GEMM to 4 then 4-wide agg. Softmax over node axis.
// ---------------------------------------------------------------------------

#define NPART 8
#define BPP   104     // blocks per partition for fill
#define T     4       // src tiles

typedef float f4 __attribute__((ext_vector_type(4)));

// ---------------- (dst, src_tile) histogram ----------------

__global__ __launch_bounds__(256) void k_count(const int* __restrict__ src,
                                               const int* __restrict__ dst,
                                               unsigned* __restrict__ cnt,
                                               int E, int chunkS) {
    int e = blockIdx.x * 256 + threadIdx.x;
    if (e >= E) return;
    int d = dst[e];
    int t = src[e] / chunkS;
    atomicAdd(&cnt[d * T + t], 1u);
}

// dinv from row extents (runs after scan)
__global__ __launch_bounds__(256) void k_dinv(const int* __restrict__ rowt,
                                              float* __restrict__ dinv, int n) {
    int i = blockIdx.x * 256 + threadIdx.x;
    if (i < n) dinv[i] = rsqrtf(1.0f + (float)(rowt[i * T + T] - rowt[i * T]));
}

// ---- hierarchical exclusive scan of cnt[0..m) -> rowt ----

__global__ __launch_bounds__(256) void k_scan1(const unsigned* __restrict__ cnt,
                                               int* __restrict__ rowt,
                                               unsigned* __restrict__ bsum, int m) {
    __shared__ unsigned t[256];
    int i = blockIdx.x * 256 + threadIdx.x;
    unsigned v = (i < m) ? cnt[i] : 0u;
    t[threadIdx.x] = v;
    __syncthreads();
    #pragma unroll
    for (int off = 1; off < 256; off <<= 1) {
        unsigned u = (threadIdx.x >= (unsigned)off) ? t[threadIdx.x - off] : 0u;
        __syncthreads();
        t[threadIdx.x] += u;
        __syncthreads();
    }
    if (i < m) rowt[i] = (int)(t[threadIdx.x] - v);
    if (threadIdx.x == 255) bsum[blockIdx.x] = t[255];
}

// robust single-block scan of bsum[0..nb) (nb may exceed 256), chunked
__global__ __launch_bounds__(256) void k_scan2(unsigned* __restrict__ bsum,
                                               int* __restrict__ rowt,
                                               int nb, int m, int E) {
    __shared__ unsigned t[256];
    unsigned run = 0;
    for (int base = 0; base < nb; base += 256) {
        int i = base + threadIdx.x;
        unsigned v = (i < nb) ? bsum[i] : 0u;
        t[threadIdx.x] = v;
        __syncthreads();
        #pragma unroll
        for (int off = 1; off < 256; off <<= 1) {
            unsigned u = (threadIdx.x >= (unsigned)off) ? t[threadIdx.x - off] : 0u;
            __syncthreads();
            t[threadIdx.x] += u;
            __syncthreads();
        }
        if (i < nb) bsum[i] = run + t[threadIdx.x] - v;   // exclusive + carry
        __syncthreads();
        run += t[255];
        __syncthreads();
    }
    if (threadIdx.x == 0) rowt[m] = E;
}

__global__ __launch_bounds__(256) void k_scan3(int* __restrict__ rowt,
                                               const unsigned* __restrict__ bsum, int m) {
    int i = blockIdx.x * 256 + threadIdx.x;
    if (i < m) rowt[i] += (int)bsum[blockIdx.x];
}

// ---- fill (XCD-partitioned by dst range; slots grouped by src tile) ----

__global__ __launch_bounds__(256) void k_fill(const int* __restrict__ src,
                                              const int* __restrict__ dst,
                                              const int* __restrict__ rowt,
                                              unsigned* __restrict__ cursor,
                                              int* __restrict__ csr_src,
                                              int E, int chunk, int chunkS) {
    int part = blockIdx.x & (NPART - 1);
    int q = blockIdx.x >> 3;
    int lo = part * chunk, hi = lo + chunk;
    for (int e = q * 256 + threadIdx.x; e < E; e += 256 * BPP) {
        int d = dst[e];
        if (d >= lo && d < hi) {
            int s = src[e];
            int slot4 = d * T + s / chunkS;
            unsigned pos = atomicAdd(&cursor[slot4], 1u);
            csr_src[rowt[slot4] + (int)pos] = s;
        }
    }
}

// ---- GEMM layer1 (128->64): 16 rows/block, 4 rows/wave, ILP-4 ----

__global__ __launch_bounds__(256) void k_gemm64_f32(const float* __restrict__ x,
                                                    const float* __restrict__ W,
                                                    const float* __restrict__ dinv,
                                                    __half* __restrict__ hs, int n) {
    __shared__ float Wl[128 * 64];
    {
        const f4* Wv = (const f4*)W;
        f4* Wlv = (f4*)Wl;
        for (int idx = threadIdx.x; idx < 128 * 16; idx += 256) Wlv[idx] = Wv[idx];
    }
    __syncthreads();
    int wave = threadIdx.x >> 6, lane = threadIdx.x & 63;
    int i0 = blockIdx.x * 16 + wave * 4;
    if (i0 >= n) return;
    if (i0 + 3 < n) {
        const f4* r0 = (const f4*)(x + (size_t)(i0 + 0) * 128);
        const f4* r1 = (const f4*)(x + (size_t)(i0 + 1) * 128);
        const f4* r2 = (const f4*)(x + (size_t)(i0 + 2) * 128);
        const f4* r3 = (const f4*)(x + (size_t)(i0 + 3) * 128);
        float a0 = 0.f, a1 = 0.f, a2 = 0.f, a3 = 0.f;
        #pragma unroll
        for (int k4 = 0; k4 < 32; ++k4) {
            f4 v0 = __builtin_nontemporal_load(&r0[k4]);
            f4 v1 = __builtin_nontemporal_load(&r1[k4]);
            f4 v2 = __builtin_nontemporal_load(&r2[k4]);
            f4 v3 = __builtin_nontemporal_load(&r3[k4]);
            float w0 = Wl[(k4 * 4 + 0) * 64 + lane];
            float w1 = Wl[(k4 * 4 + 1) * 64 + lane];
            float w2 = Wl[(k4 * 4 + 2) * 64 + lane];
            float w3 = Wl[(k4 * 4 + 3) * 64 + lane];
            a0 += v0.x * w0 + v0.y * w1 + v0.z * w2 + v0.w * w3;
            a1 += v1.x * w0 + v1.y * w1 + v1.z * w2 + v1.w * w3;
            a2 += v2.x * w0 + v2.y * w1 + v2.z * w2 + v2.w * w3;
            a3 += v3.x * w0 + v3.y * w1 + v3.z * w2 + v3.w * w3;
        }
        hs[(size_t)(i0 + 0) * 64 + lane] = __float2half(a0 * dinv[i0 + 0]);
        hs[(size_t)(i0 + 1) * 64 + lane] = __float2half(a1 * dinv[i0 + 1]);
        hs[(size_t)(i0 + 2) * 64 + lane] = __float2half(a2 * dinv[i0 + 2]);
        hs[(size_t)(i0 + 3) * 64 + lane] = __float2half(a3 * dinv[i0 + 3]);
    } else {
        for (int i = i0; i < n && i < i0 + 4; ++i) {
            const f4* r = (const f4*)(x + (size_t)i * 128);
            float acc = 0.f;
            #pragma unroll
            for (int k4 = 0; k4 < 32; ++k4) {
                f4 v = r[k4];
                acc += v.x * Wl[(k4 * 4 + 0) * 64 + lane];
                acc += v.y * Wl[(k4 * 4 + 1) * 64 + lane];
                acc += v.z * Wl[(k4 * 4 + 2) * 64 + lane];
                acc += v.w * Wl[(k4 * 4 + 3) * 64 + lane];
            }
            hs[(size_t)i * 64 + lane] = __float2half(acc * dinv[i]);
        }
    }
}

// ---- GEMM layers 2..8 (64->64 fp16 in): same structure ----

__global__ __launch_bounds__(256) void k_gemm64_f16(const __half* __restrict__ xh,
                                                    const float* __restrict__ W,
                                                    const float* __restrict__ dinv,
                                                    __half* __restrict__ hs, int n) {
    __shared__ float Wl[64 * 64];
    {
        const f4* Wv = (const f4*)W;
        f4* Wlv = (f4*)Wl;
        for (int idx = threadIdx.x; idx < 64 * 16; idx += 256) Wlv[idx] = Wv[idx];
    }
    __syncthreads();
    int wave = threadIdx.x >> 6, lane = threadIdx.x & 63;
    int i0 = blockIdx.x * 16 + wave * 4;
    if (i0 >= n) return;
    if (i0 + 3 < n) {
        const unsigned* r0 = (const unsigned*)(xh + (size_t)(i0 + 0) * 64);
        const unsigned* r1 = (const unsigned*)(xh + (size_t)(i0 + 1) * 64);
        const unsigned* r2 = (const unsigned*)(xh + (size_t)(i0 + 2) * 64);
        const unsigned* r3 = (const unsigned*)(xh + (size_t)(i0 + 3) * 64);
        float a0 = 0.f, a1 = 0.f, a2 = 0.f, a3 = 0.f;
        #pragma unroll
        for (int k2 = 0; k2 < 32; ++k2) {
            unsigned u0 = __builtin_nontemporal_load(&r0[k2]);
            unsigned u1 = __builtin_nontemporal_load(&r1[k2]);
            unsigned u2 = __builtin_nontemporal_load(&r2[k2]);
            unsigned u3 = __builtin_nontemporal_load(&r3[k2]);
            float w0 = Wl[(k2 * 2 + 0) * 64 + lane];
            float w1 = Wl[(k2 * 2 + 1) * 64 + lane];
            float2 v0 = __half22float2(*(__half2*)&u0);
            float2 v1 = __half22float2(*(__half2*)&u1);
            float2 v2 = __half22float2(*(__half2*)&u2);
            float2 v3 = __half22float2(*(__half2*)&u3);
            a0 += v0.x * w0 + v0.y * w1;
            a1 += v1.x * w0 + v1.y * w1;
            a2 += v2.x * w0 + v2.y * w1;
            a3 += v3.x * w0 + v3.y * w1;
        }
        hs[(size_t)(i0 + 0) * 64 + lane] = __float2half(a0 * dinv[i0 + 0]);
        hs[(size_t)(i0 + 1) * 64 + lane] = __float2half(a1 * dinv[i0 + 1]);
        hs[(size_t)(i0 + 2) * 64 + lane] = __float2half(a2 * dinv[i0 + 2]);
        hs[(size_t)(i0 + 3) * 64 + lane] = __float2half(a3 * dinv[i0 + 3]);
    } else {
        for (int i = i0; i < n && i < i0 + 4; ++i) {
            const __half2* r = (const __half2*)(xh + (size_t)i * 64);
            float acc = 0.f;
            #pragma unroll
            for (int k2 = 0; k2 < 32; ++k2) {
                float2 v = __half22float2(r[k2]);
                acc += v.x * Wl[(k2 * 2 + 0) * 64 + lane];
                acc += v.y * Wl[(k2 * 2 + 1) * 64 + lane];
            }
            hs[(size_t)i * 64 + lane] = __float2half(acc * dinv[i]);
        }
    }
}

// ---- small GEMM: h4[i] = (xh[i,:64] @ W[64,4]) * dinv[i] ----
__global__ __launch_bounds__(256) void k_gemm4(const __half* __restrict__ xh,
                                               const float* __restrict__ W,
                                               const float* __restrict__ dinv,
                                               float4* __restrict__ h4, int n) {
    __shared__ float Wl[256];
    for (int idx = threadIdx.x; idx < 256; idx += 256) Wl[idx] = W[idx];
    __syncthreads();
    int i = blockIdx.x * 256 + threadIdx.x;
    if (i >= n) return;
    const __half2* ar = (const __half2*)(xh + (size_t)i * 64);
    float a0 = 0.f, a1 = 0.f, a2 = 0.f, a3 = 0.f;
    #pragma unroll
    for (int k2 = 0; k2 < 32; ++k2) {
        float2 v = __half22float2(ar[k2]);
        int k = k2 * 2;
        a0 += v.x * Wl[k * 4 + 0] + v.y * Wl[(k + 1) * 4 + 0];
        a1 += v.x * Wl[k * 4 + 1] + v.y * Wl[(k + 1) * 4 + 1];
        a2 += v.x * Wl[k * 4 + 2] + v.y * Wl[(k + 1) * 4 + 2];
        a3 += v.x * Wl[k * 4 + 3] + v.y * Wl[(k + 1) * 4 + 3];
    }
    float di = dinv[i];
    h4[i] = make_float4(a0 * di, a1 * di, a2 * di, a3 * di);
}

// ------- agg 64-wide fp16 (R9 form verbatim; row extents from rowt) -------

__global__ __launch_bounds__(256) void k_agg64h(const __half* __restrict__ hs,
                                                const float* __restrict__ dinv,
                                                const int* __restrict__ rowt,
                                                const int* __restrict__ csr_src,
                                                const float* __restrict__ bias,
                                                __half* __restrict__ out, int n) {
    int wid = __builtin_amdgcn_readfirstlane((int)(threadIdx.x >> 6));
    int lane = threadIdx.x & 63;
    int gw = blockIdx.x * 4 + wid;
    if (gw >= n) return;
    float acc = __half2float(hs[(size_t)gw * 64 + lane]);  // self (prescaled)
    int s = rowt[gw * T], e = rowt[gw * T + T];
    int slot = s;
    for (; slot + 16 <= e; slot += 16) {
        int idx[16];
        #pragma unroll
        for (int j = 0; j < 16; ++j) idx[j] = csr_src[slot + j];
        float v[16];
        #pragma unroll
        for (int j = 0; j < 16; ++j) v[j] = __half2float(hs[(size_t)idx[j] * 64 + lane]);
        float t0 = ((v[0] + v[1]) + (v[2] + v[3])) + ((v[4] + v[5]) + (v[6] + v[7]));
        float t1 = ((v[8] + v[9]) + (v[10] + v[11])) + ((v[12] + v[13]) + (v[14] + v[15]));
        acc += t0 + t1;
    }
    for (; slot + 4 <= e; slot += 4) {
        int i0 = csr_src[slot + 0];
        int i1 = csr_src[slot + 1];
        int i2 = csr_src[slot + 2];
        int i3 = csr_src[slot + 3];
        float v0 = __half2float(hs[(size_t)i0 * 64 + lane]);
        float v1 = __half2float(hs[(size_t)i1 * 64 + lane]);
        float v2 = __half2float(hs[(size_t)i2 * 64 + lane]);
        float v3 = __half2float(hs[(size_t)i3 * 64 + lane]);
        acc += (v0 + v1) + (v2 + v3);
    }
    for (; slot < e; ++slot)
        acc += __half2float(hs[(size_t)csr_src[slot] * 64 + lane]);
    acc = acc * dinv[gw] + bias[lane];
    out[(size_t)gw * 64 + lane] = __float2half(fmaxf(acc, 0.f));
}

// ------- agg 4-wide (final): z[d] = (Σ h4[s] + h4[d])*dinv[d] + b3 -------

__global__ __launch_bounds__(256) void k_agg4(const float4* __restrict__ h4,
                                              const float* __restrict__ dinv,
                                              const int* __restrict__ rowt,
                                              const int* __restrict__ csr_src,
                                              const float* __restrict__ b3,
                                              float4* __restrict__ z, int n) {
    int i = blockIdx.x * 256 + threadIdx.x;
    if (i >= n) return;
    float4 self = h4[i];
    float a0 = self.x, a1 = self.y, a2 = self.z, a3 = self.w;
    int s = rowt[i * T], e = rowt[i * T + T];
    int slot = s;
    for (; slot + 4 <= e; slot += 4) {
        int s0 = csr_src[slot + 0];
        int s1 = csr_src[slot + 1];
        int s2 = csr_src[slot + 2];
        int s3 = csr_src[slot + 3];
        float4 v0 = h4[s0], v1 = h4[s1], v2 = h4[s2], v3 = h4[s3];
        a0 += v0.x + v1.x + v2.x + v3.x;
        a1 += v0.y + v1.y + v2.y + v3.y;
        a2 += v0.z + v1.z + v2.z + v3.z;
        a3 += v0.w + v1.w + v2.w + v3.w;
    }
    for (; slot < e; ++slot) {
        float4 v = h4[csr_src[slot]];
        a0 += v.x; a1 += v.y; a2 += v.z; a3 += v.w;
    }
    float di = dinv[i];
    z[i] = make_float4(a0 * di + b3[0], a1 * di + b3[1],
                       a2 * di + b3[2], a3 * di + b3[3]);
}

// ---------------- softmax over node axis (per column, C=4) ----------------

__device__ inline unsigned encf(float f) {
    unsigned u = __float_as_uint(f);
    return (u & 0x80000000u) ? ~u : (u | 0x80000000u);
}
__device__ inline float decf(unsigned e) {
    return (e & 0x80000000u) ? __uint_as_float(e & 0x7FFFFFFFu) : __uint_as_float(~e);
}

__global__ __launch_bounds__(256) void k_max(const float4* __restrict__ z,
                                             unsigned* __restrict__ gmax, int n) {
    float m0 = -FLT_MAX, m1 = -FLT_MAX, m2 = -FLT_MAX, m3 = -FLT_MAX;
    for (int i = blockIdx.x * 256 + threadIdx.x; i < n; i += gridDim.x * 256) {
        float4 v = z[i];
        m0 = fmaxf(m0, v.x); m1 = fmaxf(m1, v.y);
        m2 = fmaxf(m2, v.z); m3 = fmaxf(m3, v.w);
    }
    #pragma unroll
    for (int off = 32; off; off >>= 1) {
        m0 = fmaxf(m0, __shfl_xor(m0, off));
        m1 = fmaxf(m1, __shfl_xor(m1, off));
        m2 = fmaxf(m2, __shfl_xor(m2, off));
        m3 = fmaxf(m3, __shfl_xor(m3, off));
    }
    if ((threadIdx.x & 63) == 0) {
        atomicMax(&gmax[0], encf(m0));
        atomicMax(&gmax[1], encf(m1));
        atomicMax(&gmax[2], encf(m2));
        atomicMax(&gmax[3], encf(m3));
    }
}

__global__ __launch_bounds__(256) void k_exp(const float4* __restrict__ z,
                                             float4* __restrict__ out,
                                             const unsigned* __restrict__ gmax,
                                             float* __restrict__ gsum, int n) {
    float M0 = decf(gmax[0]), M1 = decf(gmax[1]), M2 = decf(gmax[2]), M3 = decf(gmax[3]);
    float s0 = 0.f, s1 = 0.f, s2 = 0.f, s3 = 0.f;
    for (int i = blockIdx.x * 256 + threadIdx.x; i < n; i += gridDim.x * 256) {
        float4 v = z[i];
        float4 e;
        e.x = expf(v.x - M0); e.y = expf(v.y - M1);
        e.z = expf(v.z - M2); e.w = expf(v.w - M3);
        out[i] = e;
        s0 += e.x; s1 += e.y; s2 += e.z; s3 += e.w;
    }
    #pragma unroll
    for (int off = 32; off; off >>= 1) {
        s0 += __shfl_xor(s0, off);
        s1 += __shfl_xor(s1, off);
        s2 += __shfl_xor(s2, off);
        s3 += __shfl_xor(s3, off);
    }
    if ((threadIdx.x & 63) == 0) {
        atomicAdd(&gsum[0], s0);
        atomicAdd(&gsum[1], s1);
        atomicAdd(&gsum[2], s2);
        atomicAdd(&gsum[3], s3);
    }
}

__global__ __launch_bounds__(256) void k_norm(float4* __restrict__ out,
                                              const float* __restrict__ gsum, int n) {
    float r0 = 1.f / gsum[0], r1 = 1.f / gsum[1], r2 = 1.f / gsum[2], r3 = 1.f / gsum[3];
    for (int i = blockIdx.x * 256 + threadIdx.x; i < n; i += gridDim.x * 256) {
        float4 v = out[i];
        v.x *= r0; v.y *= r1; v.z *= r2; v.w *= r3;
        out[i] = v;
    }
}

// ---------------------------------------------------------------------------

extern "C" void kernel_launch(void* const* d_in, const int* in_sizes, int n_in,
                              void* d_out, int out_size, void* d_ws, size_t ws_size,
                              hipStream_t stream) {
    const float* x0 = (const float*)d_in[0];
    const int* ei = (const int*)d_in[1];
    const float* W1 = (const float*)d_in[2];
    const float* b1 = (const float*)d_in[3];
    const float* W2 = (const float*)d_in[4];
    const float* b2 = (const float*)d_in[5];
    const float* W3 = (const float*)d_in[6];
    const float* b3 = (const float*)d_in[7];

    const int n = in_sizes[0] / 128;   // 50000
    const int E = in_sizes[1] / 2;     // 1600000
    const int* src = ei;
    const int* dst = ei + E;
    const int chunk = (n + NPART - 1) / NPART;   // dst partition size
    const int chunkS = (n + T - 1) / T;          // src tile size
    const int m = n * T;                         // (dst, tile) cells

    char* ws = (char*)d_ws;
    size_t off = 0;
    auto alloc = [&](size_t bytes) -> void* {
        void* p = (void*)(ws + off);
        off = (off + bytes + 255) & ~(size_t)255;
        return p;
    };

    // zeroed region first (cnt, cursor, gmax, gsum)
    unsigned* cnt    = (unsigned*)alloc((size_t)m * 4);
    unsigned* cursor = (unsigned*)alloc((size_t)m * 4);
    unsigned* gmax   = (unsigned*)alloc(16);
    float*    gsum   = (float*)alloc(16);
    size_t zero_bytes = off;

    float* dinv      = (float*)alloc((size_t)n * 4);
    int*   rowt      = (int*)alloc((size_t)(m + 1) * 4);
    unsigned* bsum   = (unsigned*)alloc(1024 * 4);
    int*   csr_src   = (int*)alloc((size_t)E * 4);
    __half* hbuf     = (__half*)alloc((size_t)n * 64 * 2);
    __half* xbuf     = (__half*)alloc((size_t)n * 64 * 2);
    float4* h4buf    = (float4*)alloc((size_t)n * 16);
    float4* zbuf     = (float4*)alloc((size_t)n * 16);

    hipMemsetAsync(cnt, 0, zero_bytes, stream);

    const int nbN = (n + 255) / 256;
    const int nbE = (E + 255) / 256;
    const int nbM = (m + 255) / 256;

    // CSR build: (dst,tile) histogram -> scan -> dinv -> partitioned fill
    k_count<<<nbE, 256, 0, stream>>>(src, dst, cnt, E, chunkS);
    k_scan1<<<nbM, 256, 0, stream>>>(cnt, rowt, bsum, m);
    k_scan2<<<1, 256, 0, stream>>>(bsum, rowt, nbM, m, E);
    k_scan3<<<nbM, 256, 0, stream>>>(rowt, bsum, m);
    k_dinv<<<nbN, 256, 0, stream>>>(rowt, dinv, n);
    k_fill<<<NPART * BPP, 256, 0, stream>>>(src, dst, rowt, cursor, csr_src, E, chunk, chunkS);

    const int nbG = (n + 15) / 16;        // gemm blocks (16 rows/block)
    const int nbA = (n + 3) / 4;          // agg blocks (4 waves/block)

    // layer 1: 128 -> 64 (fp32 input)
    k_gemm64_f32<<<nbG, 256, 0, stream>>>(x0, W1, dinv, hbuf, n);
    k_agg64h<<<nbA, 256, 0, stream>>>(hbuf, dinv, rowt, csr_src, b1, xbuf, n);

    // layers 2..8: 64 -> 64, shared W2 (fp16 activations)
    for (int l = 0; l < 7; ++l) {
        k_gemm64_f16<<<nbG, 256, 0, stream>>>(xbuf, W2, dinv, hbuf, n);
        k_agg64h<<<nbA, 256, 0, stream>>>(hbuf, dinv, rowt, csr_src, b2, xbuf, n);
    }

    // layer 9: gemm to 4 features first, then 4-wide agg (fp32)
    k_gemm4<<<nbN, 256, 0, stream>>>(xbuf, W3, dinv, h4buf, n);
    k_agg4<<<nbN, 256, 0, stream>>>(h4buf, dinv, rowt, csr_src, b3, zbuf, n);

    // softmax over node axis
    k_max<<<256, 256, 0, stream>>>(zbuf, gmax, n);
    k_exp<<<256, 256, 0, stream>>>(zbuf, (float4*)d_out, gmax, gsum, n);
    k_norm<<<256, 256, 0, stream>>>((float4*)d_out, gsum, n);
}